// Round 8
// baseline (19296.416 us; speedup 1.0000x reference)
//
#include <hip/hip_runtime.h>
#include <hip/hip_cooperative_groups.h>
#include <stdint.h>

#define NPART 64
#define NBATCH 32
#define NSEQ 128
#define NEIN 64
#define NHID 256

namespace cg = cooperative_groups;

// ---------------- JAX threefry2x32 (bit-exact) ----------------
__device__ __forceinline__ uint32_t rotl32(uint32_t x, uint32_t d) {
  return (x << d) | (x >> (32u - d));
}

__device__ __forceinline__ void threefry2x32(uint32_t k0, uint32_t k1,
                                             uint32_t& x0, uint32_t& x1) {
  uint32_t k2 = k0 ^ k1 ^ 0x1BD11BDAu;
  x0 += k0; x1 += k1;
#define TFR(r) { x0 += x1; x1 = rotl32(x1, r); x1 ^= x0; }
  TFR(13u) TFR(15u) TFR(26u) TFR(6u)
  x0 += k1; x1 += k2 + 1u;
  TFR(17u) TFR(29u) TFR(16u) TFR(24u)
  x0 += k2; x1 += k0 + 2u;
  TFR(13u) TFR(15u) TFR(26u) TFR(6u)
  x0 += k0; x1 += k1 + 3u;
  TFR(17u) TFR(29u) TFR(16u) TFR(24u)
  x0 += k1; x1 += k2 + 4u;
  TFR(13u) TFR(15u) TFR(26u) TFR(6u)
  x0 += k2; x1 += k0 + 5u;
#undef TFR
}

__device__ __forceinline__ float lreluf(float x) { return x >= 0.f ? x : 0.01f * x; }

// ---------------- prep: float4 gate-quad repack, state init, key chain -------
__global__ void k_prep(const float* __restrict__ h0, const float* __restrict__ c0,
                       const float* __restrict__ W_ih, const float* __restrict__ W_hh,
                       float* __restrict__ hA, float* __restrict__ cA,
                       float4* __restrict__ Wih4, float4* __restrict__ Whh4,
                       float* __restrict__ p_cur, float* __restrict__ y_acc,
                       int* __restrict__ idx_buf, uint2* __restrict__ subs) {
  int tid = blockIdx.x * blockDim.x + threadIdx.x;
  int nthr = gridDim.x * blockDim.x;
  for (int i = tid; i < NPART * NBATCH * NHID; i += nthr) {
    hA[i] = h0[i];
    cA[i] = c0[i];
  }
  for (int i = tid; i < NEIN * NHID; i += nthr) {
    int e = i >> 8, j = i & 255;
    Wih4[i] = make_float4(W_ih[j * NEIN + e], W_ih[(256 + j) * NEIN + e],
                          W_ih[(512 + j) * NEIN + e], W_ih[(768 + j) * NEIN + e]);
  }
  for (int i = tid; i < NHID * NHID; i += nthr) {
    int k = i >> 8, j = i & 255;
    Whh4[i] = make_float4(W_hh[j * NHID + k], W_hh[(256 + j) * NHID + k],
                          W_hh[(512 + j) * NHID + k], W_hh[(768 + j) * NHID + k]);
  }
  for (int i = tid; i < NPART * NBATCH; i += nthr) {
    p_cur[i] = -4.1588830833596715f;  // fp32(log(1/64))
    idx_buf[i] = i >> 5;              // identity resample for t=0 gather
  }
  for (int i = tid; i < NBATCH; i += nthr) y_acc[i] = 0.f;
  if (tid < NSEQ) {
    uint32_t k0u = 0u, k1u = 42u, sx = 0u, sy = 0u;
    for (int i = 0; i <= tid; ++i) {
      uint32_t s0 = 0u, s1 = 1u; threefry2x32(k0u, k1u, s0, s1);
      uint32_t n0 = 0u, n1 = 0u; threefry2x32(k0u, k1u, n0, n1);
      sx = s0; sy = s1; k0u = n0; k1u = n1;
    }
    subs[tid] = make_uint2(sx, sy);
  }
}

// ---------------- fused persistent kernel: all 128 steps, 2 grid syncs/step --
// 512 blocks x 256 thr = exactly 2 blocks/CU (co-resident; launch_bounds caps
// VGPR<=128, LDS 17.6KB). Phase 1 = round-7 k_step body verbatim (all blocks).
// Phase 2 = validated k_pf body on blocks 0..31, remapped 8 waves -> 4 waves
// x 2 passes (per-value math and shfl trees unchanged -> bit-exact).
// Eliminates 254 kernel launches (measured ~12-15us/launch drain tax).
// Host falls back to per-step launches if cooperative launch is rejected.
__global__ __launch_bounds__(256, 2)
void k_main(const float* __restrict__ obs,
            float* __restrict__ hA, float* __restrict__ hB,
            float* __restrict__ cA, float* __restrict__ cB,
            const float4* __restrict__ Wih4, const float4* __restrict__ Whh4,
            const float* __restrict__ b_ih, const float* __restrict__ b_hh,
            const float* __restrict__ W_obs, const float* __restrict__ b_obs_p,
            const float* __restrict__ W_out, const float* __restrict__ b_out_p,
            float* __restrict__ p_cur, int* __restrict__ idx_buf,
            const uint2* __restrict__ subs, float* __restrict__ y_acc,
            float* __restrict__ d_out) {
  cg::grid_group grid = cg::this_grid();
  __shared__ float h_s[16][NHID];      // 16 KB
  __shared__ float obs_s[NEIN];
  __shared__ int src_s[16];
  __shared__ float logp_s[NPART], p1_s[NPART], lg_s[NPART], pdot_s[NPART];
  __shared__ int idx_s[NPART];
  __shared__ float lx_s;

  const int tid = threadIdx.x;
  const int bid = blockIdx.x;
  const int cb = bid & 3;            // 0..3 -> h-dims [cb*64, cb*64+64)
  const int rb = bid >> 2;           // 0..127
  const int b = rb >> 2;             // batch for phase 1
  const int qg = rb & 3;
  const int jloc = tid & 63;
  const int rg = tid >> 6;           // wave id = row group (4 rows each)
  const int jglob = cb * 64 + jloc;
  const int lane = tid & 63;
  const int wv = tid >> 6;           // 0..3

  for (int t = 0; t < NSEQ; ++t) {
    const float* h_prev = (t & 1) ? hB : hA;
    float* h_out        = (t & 1) ? hA : hB;
    const float* c_prev = (t & 1) ? cB : cA;
    float* c_out        = (t & 1) ? cA : cB;

    // ================= phase 1: gates GEMM + LSTM pointwise =================
    if (t > 0 && bid == 0 && tid < NBATCH) {
      d_out[(t - 1) * NBATCH + tid] = lreluf(y_acc[tid] + b_out_p[0]);
      y_acc[tid] = 0.f;
    }
    if (tid < NEIN) obs_s[tid] = obs[(b * NSEQ + t) * NEIN + tid];
    if (tid < 16) {
      int q = qg * 16 + tid;
      src_s[tid] = idx_buf[q * NBATCH + b] * NBATCH + b;
    }
    __syncthreads();

    for (int i = tid; i < 16 * (NHID / 4); i += 256) {
      int r = i >> 6, kq = i & 63;
      ((float4*)h_s[r])[kq] = ((const float4*)(h_prev + src_s[r] * NHID))[kq];
    }

    float xb[4];
    {
      float4 w0 = make_float4(b_ih[jglob] + b_hh[jglob],
                              b_ih[jglob + 256] + b_hh[jglob + 256],
                              b_ih[jglob + 512] + b_hh[jglob + 512],
                              b_ih[jglob + 768] + b_hh[jglob + 768]);
      xb[0] = w0.x; xb[1] = w0.y; xb[2] = w0.z; xb[3] = w0.w;
    }
#pragma unroll 8
    for (int e = 0; e < NEIN; ++e) {
      float xv = obs_s[e];
      float4 w = Wih4[e * NHID + jglob];
      xb[0] += xv * w.x;
      xb[1] += xv * w.y;
      xb[2] += xv * w.z;
      xb[3] += xv * w.w;
    }

    float acc[4][4];
#pragma unroll
    for (int rr = 0; rr < 4; ++rr)
#pragma unroll
      for (int g = 0; g < 4; ++g) acc[rr][g] = 0.f;

    const float4* hrow4[4];
#pragma unroll
    for (int rr = 0; rr < 4; ++rr) hrow4[rr] = (const float4*)h_s[rg * 4 + rr];

    __syncthreads();  // h_s resident; K-loop below is barrier-free

    const float4* __restrict__ pW = Whh4 + cb * 64 + jloc;  // stride 256/k
#pragma unroll 2
    for (int k4 = 0; k4 < 64; ++k4) {   // 4 k at a time, k ascending
      float4 h4[4], w4[4];
#pragma unroll
      for (int rr = 0; rr < 4; ++rr) h4[rr] = hrow4[rr][k4];
#pragma unroll
      for (int kk = 0; kk < 4; ++kk) w4[kk] = pW[(k4 * 4 + kk) * 256];
#pragma unroll
      for (int kk = 0; kk < 4; ++kk) {
#pragma unroll
        for (int rr = 0; rr < 4; ++rr) {
          float hv = ((const float*)&h4[rr])[kk];
          acc[rr][0] += hv * w4[kk].x;
          acc[rr][1] += hv * w4[kk].y;
          acc[rr][2] += hv * w4[kk].z;
          acc[rr][3] += hv * w4[kk].w;
        }
      }
    }

#pragma unroll
    for (int rr = 0; rr < 4; ++rr) {
      int q = qg * 16 + rg * 4 + rr;
      int n = q * NBATCH + b;
      float iv = acc[rr][0] + xb[0];
      float fv = acc[rr][1] + xb[1];
      float gv = acc[rr][2] + xb[2];
      float ov = acc[rr][3] + xb[3];
      float cp = c_prev[src_s[rg * 4 + rr] * NHID + jglob];
      float si = 1.f / (1.f + expf(-iv));
      float sf = 1.f / (1.f + expf(-fv));
      float so = 1.f / (1.f + expf(-ov));
      float c1 = sf * cp + si * tanhf(gv);
      float h1 = so * tanhf(c1);
      h_out[n * NHID + jglob] = h1;
      c_out[n * NHID + jglob] = c1;
    }

    grid.sync();  // h_out complete, visible grid-wide

    // ================= phase 2: pf (blocks 0..31, 4 waves x 2 passes) =======
    if (bid < NBATCH) {
      const int b2 = bid;
      float Wo[4], Wu[4];
#pragma unroll
      for (int m = 0; m < 4; ++m) {
        Wo[m] = W_obs[NEIN + m * 64 + lane];
        Wu[m] = W_out[m * 64 + lane];
      }
      if (wv == 0) {
        float v = obs[(b2 * NSEQ + t) * NEIN + lane] * W_obs[lane];
#pragma unroll
        for (int off = 32; off > 0; off >>= 1) v += __shfl_down(v, off, 64);
        if (lane == 0) lx_s = v + b_obs_p[0];
      }
      for (int ps = 0; ps < 2; ++ps) {
        const int wv2 = wv + 4 * ps;
        float hv[8][4];
#pragma unroll
        for (int u = 0; u < 8; ++u) {
          const float* hr = h_out + ((wv2 * 8 + u) * NBATCH + b2) * NHID;
#pragma unroll
          for (int m = 0; m < 4; ++m) hv[u][m] = hr[m * 64 + lane];
        }
#pragma unroll
        for (int u = 0; u < 8; ++u) {
          float hp = 0.f;
#pragma unroll
          for (int m = 0; m < 4; ++m) hp += hv[u][m] * Wo[m];
#pragma unroll
          for (int off = 32; off > 0; off >>= 1) hp += __shfl_down(hp, off, 64);
          if (lane == 0) logp_s[wv2 * 8 + u] = hp;
        }
#pragma unroll
        for (int u = 0; u < 8; ++u) {
          float pd = 0.f;
#pragma unroll
          for (int m = 0; m < 4; ++m) pd += hv[u][m] * Wu[m];
#pragma unroll
          for (int off = 32; off > 0; off >>= 1) pd += __shfl_down(pd, off, 64);
          if (lane == 0) pdot_s[wv2 * 8 + u] = pd;
        }
      }
      __syncthreads();

      if (wv == 0) {
        int n = lane * NBATCH + b2;
        float x = logp_s[lane] + lx_s + p_cur[n];
        float m = x;
#pragma unroll
        for (int off = 32; off > 0; off >>= 1) {
          float o = __shfl_xor(m, off, 64);
          m = o > m ? o : m;
        }
        float s = expf(x - m);
#pragma unroll
        for (int off = 32; off > 0; off >>= 1) s += __shfl_xor(s, off, 64);
        float p1 = x - m - logf(s);
        p1_s[lane] = p1;
        lg_s[lane] = logf(0.1f * expf(p1) + 0.9f / 64.f);
      }
      __syncthreads();

      const uint2 sub = subs[t];
      for (int ps = 0; ps < 2; ++ps) {
        const int wv2 = wv + 4 * ps;
        float v[8]; int id[8];
#pragma unroll
        for (int u = 0; u < 8; ++u) {
          int q = wv2 * 8 + u;
          uint32_t x0 = 0u;
          uint32_t x1 = (uint32_t)((q * NBATCH + b2) * NPART + lane);
          threefry2x32(sub.x, sub.y, x0, x1);
          uint32_t bits = x0 ^ x1;
          uint32_t mant = bits >> 9;
          float uu = (mant == 0u) ? 1.17549435e-38f
                                  : (float)mant * 1.1920928955078125e-07f;
          float g = -logf(-logf(uu));
          v[u] = g + lg_s[lane];
          id[u] = lane;
        }
#pragma unroll
        for (int off = 32; off > 0; off >>= 1) {
#pragma unroll
          for (int u = 0; u < 8; ++u) {
            float ov = __shfl_xor(v[u], off, 64);
            int oi = __shfl_xor(id[u], off, 64);
            if (ov > v[u] || (ov == v[u] && oi < id[u])) { v[u] = ov; id[u] = oi; }
          }
        }
        if (lane == 0) {
#pragma unroll
          for (int u = 0; u < 8; ++u) idx_s[wv2 * 8 + u] = id[u];
        }
      }
      __syncthreads();

      if (wv == 0) {
        int src = idx_s[lane];
        int n = lane * NBATCH + b2;
        idx_buf[n] = src;
        float wn = 0.1f * expf(p1_s[src]) + 0.9f / 64.f;
        float lw = logf(wn);
        float m = lw;
#pragma unroll
        for (int off = 32; off > 0; off >>= 1) {
          float o = __shfl_xor(m, off, 64);
          m = o > m ? o : m;
        }
        float s = expf(lw - m);
#pragma unroll
        for (int off = 32; off > 0; off >>= 1) s += __shfl_xor(s, off, 64);
        float pn = lw - m - logf(s);
        p_cur[n] = pn;
        float pd = pdot_s[src];  // bit-identical to dot(h1[src*B+b], W_out)
        d_out[NSEQ * NBATCH + t * (NPART * NBATCH) + lane * NBATCH + b2] =
            lreluf(pd + b_out_p[0]);
        float yv = expf(pn) * pd;
#pragma unroll
        for (int off = 32; off > 0; off >>= 1) yv += __shfl_down(yv, off, 64);
        if (lane == 0) y_acc[b2] += yv;
      }
    }
    grid.sync();  // idx_buf/p_cur/y_acc visible for next step
  }
  if (bid == 0 && tid < NBATCH) {
    d_out[(NSEQ - 1) * NBATCH + tid] = lreluf(y_acc[tid] + b_out_p[0]);
  }
}

// ---------------- fallback per-step kernels (round-7 validated path) ---------
__global__ __launch_bounds__(256, 2)
void k_step(int t,
            const float* __restrict__ h_prev, const float* __restrict__ c_prev,
            float* __restrict__ h_out, float* __restrict__ c_out,
            const int* __restrict__ idx_buf, const float* __restrict__ obs,
            const float4* __restrict__ Wih4, const float4* __restrict__ Whh4,
            const float* __restrict__ b_ih, const float* __restrict__ b_hh,
            float* __restrict__ y_acc, const float* __restrict__ b_out_p,
            float* __restrict__ d_out) {
  __shared__ float h_s[16][NHID];
  __shared__ float obs_s[NEIN];
  __shared__ int src_s[16];
  const int tid = threadIdx.x;
  const int cb = blockIdx.x;
  const int rb = blockIdx.y;
  const int b = rb >> 2;
  const int qg = rb & 3;
  const int jloc = tid & 63;
  const int rg = tid >> 6;
  const int jglob = cb * 64 + jloc;

  if (t > 0 && cb == 0 && rb == 0 && tid < NBATCH) {
    d_out[(t - 1) * NBATCH + tid] = lreluf(y_acc[tid] + b_out_p[0]);
    y_acc[tid] = 0.f;
  }
  if (tid < NEIN) obs_s[tid] = obs[(b * NSEQ + t) * NEIN + tid];
  if (tid < 16) {
    int q = qg * 16 + tid;
    src_s[tid] = idx_buf[q * NBATCH + b] * NBATCH + b;
  }
  __syncthreads();
  for (int i = tid; i < 16 * (NHID / 4); i += 256) {
    int r = i >> 6, kq = i & 63;
    ((float4*)h_s[r])[kq] = ((const float4*)(h_prev + src_s[r] * NHID))[kq];
  }
  float xb[4];
  {
    float4 w0 = make_float4(b_ih[jglob] + b_hh[jglob],
                            b_ih[jglob + 256] + b_hh[jglob + 256],
                            b_ih[jglob + 512] + b_hh[jglob + 512],
                            b_ih[jglob + 768] + b_hh[jglob + 768]);
    xb[0] = w0.x; xb[1] = w0.y; xb[2] = w0.z; xb[3] = w0.w;
  }
#pragma unroll 8
  for (int e = 0; e < NEIN; ++e) {
    float xv = obs_s[e];
    float4 w = Wih4[e * NHID + jglob];
    xb[0] += xv * w.x;
    xb[1] += xv * w.y;
    xb[2] += xv * w.z;
    xb[3] += xv * w.w;
  }
  float acc[4][4];
#pragma unroll
  for (int rr = 0; rr < 4; ++rr)
#pragma unroll
    for (int g = 0; g < 4; ++g) acc[rr][g] = 0.f;
  const float4* hrow4[4];
#pragma unroll
  for (int rr = 0; rr < 4; ++rr) hrow4[rr] = (const float4*)h_s[rg * 4 + rr];
  __syncthreads();
  const float4* __restrict__ pW = Whh4 + cb * 64 + jloc;
#pragma unroll 2
  for (int k4 = 0; k4 < 64; ++k4) {
    float4 h4[4], w4[4];
#pragma unroll
    for (int rr = 0; rr < 4; ++rr) h4[rr] = hrow4[rr][k4];
#pragma unroll
    for (int kk = 0; kk < 4; ++kk) w4[kk] = pW[(k4 * 4 + kk) * 256];
#pragma unroll
    for (int kk = 0; kk < 4; ++kk) {
#pragma unroll
      for (int rr = 0; rr < 4; ++rr) {
        float hv = ((const float*)&h4[rr])[kk];
        acc[rr][0] += hv * w4[kk].x;
        acc[rr][1] += hv * w4[kk].y;
        acc[rr][2] += hv * w4[kk].z;
        acc[rr][3] += hv * w4[kk].w;
      }
    }
  }
#pragma unroll
  for (int rr = 0; rr < 4; ++rr) {
    int q = qg * 16 + rg * 4 + rr;
    int n = q * NBATCH + b;
    float iv = acc[rr][0] + xb[0];
    float fv = acc[rr][1] + xb[1];
    float gv = acc[rr][2] + xb[2];
    float ov = acc[rr][3] + xb[3];
    float cp = c_prev[src_s[rg * 4 + rr] * NHID + jglob];
    float si = 1.f / (1.f + expf(-iv));
    float sf = 1.f / (1.f + expf(-fv));
    float so = 1.f / (1.f + expf(-ov));
    float c1 = sf * cp + si * tanhf(gv);
    float h1 = so * tanhf(c1);
    h_out[n * NHID + jglob] = h1;
    c_out[n * NHID + jglob] = c1;
  }
}

__global__ __launch_bounds__(512)
void k_pf(int t, const float* __restrict__ obs, const float* __restrict__ W_obs,
          const float* __restrict__ b_obs_p, const float* __restrict__ h1,
          float* __restrict__ p_cur, int* __restrict__ idx_buf,
          const uint2* __restrict__ subs, const float* __restrict__ W_out,
          const float* __restrict__ b_out_p, float* __restrict__ y_acc,
          float* __restrict__ d_out) {
  __shared__ float logp_s[NPART], p1_s[NPART], lg_s[NPART], pdot_s[NPART];
  __shared__ int idx_s[NPART];
  __shared__ float lx_s;
  const int tid = threadIdx.x;
  const int lane = tid & 63;
  const int wv = tid >> 6;
  const int b = blockIdx.x;

  float Wo[4], Wu[4];
#pragma unroll
  for (int m = 0; m < 4; ++m) {
    Wo[m] = W_obs[NEIN + m * 64 + lane];
    Wu[m] = W_out[m * 64 + lane];
  }
  if (wv == 0) {
    float v = obs[(b * NSEQ + t) * NEIN + lane] * W_obs[lane];
#pragma unroll
    for (int off = 32; off > 0; off >>= 1) v += __shfl_down(v, off, 64);
    if (lane == 0) lx_s = v + b_obs_p[0];
  }
  {
    float hv[8][4];
#pragma unroll
    for (int u = 0; u < 8; ++u) {
      const float* hr = h1 + ((wv * 8 + u) * NBATCH + b) * NHID;
#pragma unroll
      for (int m = 0; m < 4; ++m) hv[u][m] = hr[m * 64 + lane];
    }
#pragma unroll
    for (int u = 0; u < 8; ++u) {
      float hp = 0.f;
#pragma unroll
      for (int m = 0; m < 4; ++m) hp += hv[u][m] * Wo[m];
#pragma unroll
      for (int off = 32; off > 0; off >>= 1) hp += __shfl_down(hp, off, 64);
      if (lane == 0) logp_s[wv * 8 + u] = hp;
    }
#pragma unroll
    for (int u = 0; u < 8; ++u) {
      float pd = 0.f;
#pragma unroll
      for (int m = 0; m < 4; ++m) pd += hv[u][m] * Wu[m];
#pragma unroll
      for (int off = 32; off > 0; off >>= 1) pd += __shfl_down(pd, off, 64);
      if (lane == 0) pdot_s[wv * 8 + u] = pd;
    }
  }
  __syncthreads();

  if (wv == 0) {
    int n = lane * NBATCH + b;
    float x = logp_s[lane] + lx_s + p_cur[n];
    float m = x;
#pragma unroll
    for (int off = 32; off > 0; off >>= 1) {
      float o = __shfl_xor(m, off, 64);
      m = o > m ? o : m;
    }
    float s = expf(x - m);
#pragma unroll
    for (int off = 32; off > 0; off >>= 1) s += __shfl_xor(s, off, 64);
    float p1 = x - m - logf(s);
    p1_s[lane] = p1;
    lg_s[lane] = logf(0.1f * expf(p1) + 0.9f / 64.f);
  }
  __syncthreads();

  const uint2 sub = subs[t];
  {
    float v[8]; int id[8];
#pragma unroll
    for (int u = 0; u < 8; ++u) {
      int q = wv * 8 + u;
      uint32_t x0 = 0u;
      uint32_t x1 = (uint32_t)((q * NBATCH + b) * NPART + lane);
      threefry2x32(sub.x, sub.y, x0, x1);
      uint32_t bits = x0 ^ x1;
      uint32_t mant = bits >> 9;
      float uu = (mant == 0u) ? 1.17549435e-38f
                              : (float)mant * 1.1920928955078125e-07f;
      float g = -logf(-logf(uu));
      v[u] = g + lg_s[lane];
      id[u] = lane;
    }
#pragma unroll
    for (int off = 32; off > 0; off >>= 1) {
#pragma unroll
      for (int u = 0; u < 8; ++u) {
        float ov = __shfl_xor(v[u], off, 64);
        int oi = __shfl_xor(id[u], off, 64);
        if (ov > v[u] || (ov == v[u] && oi < id[u])) { v[u] = ov; id[u] = oi; }
      }
    }
    if (lane == 0) {
#pragma unroll
      for (int u = 0; u < 8; ++u) idx_s[wv * 8 + u] = id[u];
    }
  }
  __syncthreads();

  if (wv == 0) {
    int src = idx_s[lane];
    int n = lane * NBATCH + b;
    idx_buf[n] = src;
    float wn = 0.1f * expf(p1_s[src]) + 0.9f / 64.f;
    float lw = logf(wn);
    float m = lw;
#pragma unroll
    for (int off = 32; off > 0; off >>= 1) {
      float o = __shfl_xor(m, off, 64);
      m = o > m ? o : m;
    }
    float s = expf(lw - m);
#pragma unroll
    for (int off = 32; off > 0; off >>= 1) s += __shfl_xor(s, off, 64);
    float pn = lw - m - logf(s);
    p_cur[n] = pn;
    float pd = pdot_s[src];
    d_out[NSEQ * NBATCH + t * (NPART * NBATCH) + lane * NBATCH + b] =
        lreluf(pd + b_out_p[0]);
    float yv = expf(pn) * pd;
#pragma unroll
    for (int off = 32; off > 0; off >>= 1) yv += __shfl_down(yv, off, 64);
    if (lane == 0) y_acc[b] += yv;
  }
}

__global__ void k_final(const float* __restrict__ y_acc,
                        const float* __restrict__ b_out_p, float* __restrict__ d_out) {
  int b = threadIdx.x;
  if (b < NBATCH) {
    d_out[(NSEQ - 1) * NBATCH + b] = lreluf(y_acc[b] + b_out_p[0]);
  }
}

extern "C" void kernel_launch(void* const* d_in, const int* in_sizes, int n_in,
                              void* d_out, int out_size, void* d_ws, size_t ws_size,
                              hipStream_t stream) {
  const float* obs   = (const float*)d_in[0];
  const float* h0    = (const float*)d_in[1];
  const float* c0    = (const float*)d_in[2];
  const float* W_ih  = (const float*)d_in[3];
  const float* b_ih  = (const float*)d_in[4];
  const float* W_hh  = (const float*)d_in[5];
  const float* b_hh  = (const float*)d_in[6];
  const float* W_obs = (const float*)d_in[7];
  const float* b_obs = (const float*)d_in[8];
  const float* W_out = (const float*)d_in[9];
  const float* b_out = (const float*)d_in[10];
  float* out = (float*)d_out;

  char* w = (char*)d_ws;
  const size_t state = (size_t)NPART * NBATCH * NHID * sizeof(float);  // 2 MB
  float* hA = (float*)w;        w += state;
  float* hB = (float*)w;        w += state;
  float* cA = (float*)w;        w += state;
  float* cB = (float*)w;        w += state;
  float* p_cur = (float*)w;     w += NPART * NBATCH * sizeof(float);
  float* y_acc = (float*)w;     w += NBATCH * sizeof(float);
  uint2* subs = (uint2*)w;      w += NSEQ * sizeof(uint2);
  float4* Wih4 = (float4*)w;    w += NEIN * NHID * sizeof(float4);
  float4* Whh4 = (float4*)w;    w += NHID * NHID * sizeof(float4);
  int* idx_buf = (int*)w;       w += NPART * NBATCH * sizeof(int);

  k_prep<<<dim3(256), dim3(256), 0, stream>>>(h0, c0, W_ih, W_hh, hA, cA, Wih4, Whh4,
                                              p_cur, y_acc, idx_buf, subs);

  // primary path: one persistent cooperative kernel for all 128 steps
  {
    void* ka[] = {(void*)&obs, (void*)&hA, (void*)&hB, (void*)&cA, (void*)&cB,
                  (void*)&Wih4, (void*)&Whh4, (void*)&b_ih, (void*)&b_hh,
                  (void*)&W_obs, (void*)&b_obs, (void*)&W_out, (void*)&b_out,
                  (void*)&p_cur, (void*)&idx_buf, (void*)&subs, (void*)&y_acc,
                  (void*)&out};
    hipError_t err = hipLaunchCooperativeKernel(
        reinterpret_cast<void*>(k_main), dim3(512), dim3(256), ka, 0, stream);
    if (err == hipSuccess) return;
    (void)hipGetLastError();  // clear error, fall back to per-step launches
  }

  // fallback: round-7 validated per-step path
  for (int t = 0; t < NSEQ; ++t) {
    const float* hp = (t & 1) ? hB : hA;
    float* hn       = (t & 1) ? hA : hB;
    const float* cp = (t & 1) ? cB : cA;
    float* cn       = (t & 1) ? cA : cB;
    k_step<<<dim3(4, 128), dim3(256), 0, stream>>>(
        t, hp, cp, hn, cn, idx_buf, obs, Wih4, Whh4, b_ih, b_hh, y_acc, b_out, out);
    k_pf<<<dim3(NBATCH), dim3(512), 0, stream>>>(
        t, obs, W_obs, b_obs, hn, p_cur, idx_buf, subs, W_out, b_out, y_acc, out);
  }
  k_final<<<dim3(1), dim3(64), 0, stream>>>(y_acc, b_out, out);
}

// Round 9
// 6064.511 us; speedup vs baseline: 3.1819x; 3.1819x over previous
//
#include <hip/hip_runtime.h>
#include <stdint.h>

#define NPART 64
#define NBATCH 32
#define NSEQ 128
#define NEIN 64
#define NHID 256

// ---------------- JAX threefry2x32 (bit-exact) ----------------
__device__ __forceinline__ uint32_t rotl32(uint32_t x, uint32_t d) {
  return (x << d) | (x >> (32u - d));
}

__device__ __forceinline__ void threefry2x32(uint32_t k0, uint32_t k1,
                                             uint32_t& x0, uint32_t& x1) {
  uint32_t k2 = k0 ^ k1 ^ 0x1BD11BDAu;
  x0 += k0; x1 += k1;
#define TFR(r) { x0 += x1; x1 = rotl32(x1, r); x1 ^= x0; }
  TFR(13u) TFR(15u) TFR(26u) TFR(6u)
  x0 += k1; x1 += k2 + 1u;
  TFR(17u) TFR(29u) TFR(16u) TFR(24u)
  x0 += k2; x1 += k0 + 2u;
  TFR(13u) TFR(15u) TFR(26u) TFR(6u)
  x0 += k0; x1 += k1 + 3u;
  TFR(17u) TFR(29u) TFR(16u) TFR(24u)
  x0 += k1; x1 += k2 + 4u;
  TFR(13u) TFR(15u) TFR(26u) TFR(6u)
  x0 += k2; x1 += k0 + 5u;
#undef TFR
}

__device__ __forceinline__ float lreluf(float x) { return x >= 0.f ? x : 0.01f * x; }

// ---------------- prep: float4 gate-quad repack, state init, key chain -------
__global__ void k_prep(const float* __restrict__ h0, const float* __restrict__ c0,
                       const float* __restrict__ W_ih, const float* __restrict__ W_hh,
                       float* __restrict__ hA, float* __restrict__ cA,
                       float4* __restrict__ Wih4, float4* __restrict__ Whh4,
                       float* __restrict__ pA, float* __restrict__ pB,
                       uint2* __restrict__ subs) {
  int tid = blockIdx.x * blockDim.x + threadIdx.x;
  int nthr = gridDim.x * blockDim.x;
  for (int i = tid; i < NPART * NBATCH * NHID; i += nthr) {
    hA[i] = h0[i];
    cA[i] = c0[i];
  }
  for (int i = tid; i < NEIN * NHID; i += nthr) {
    int e = i >> 8, j = i & 255;
    Wih4[i] = make_float4(W_ih[j * NEIN + e], W_ih[(256 + j) * NEIN + e],
                          W_ih[(512 + j) * NEIN + e], W_ih[(768 + j) * NEIN + e]);
  }
  for (int i = tid; i < NHID * NHID; i += nthr) {
    int k = i >> 8, j = i & 255;
    Whh4[i] = make_float4(W_hh[j * NHID + k], W_hh[(256 + j) * NHID + k],
                          W_hh[(512 + j) * NHID + k], W_hh[(768 + j) * NHID + k]);
  }
  for (int i = tid; i < NPART * NBATCH; i += nthr) {
    pA[i] = -4.1588830833596715f;  // fp32(log(1/64))
    pB[i] = -4.1588830833596715f;
  }
  if (tid < NSEQ) {
    // threefry_partitionable split: key' = tf(key,(0,0)), sub = tf(key,(0,1))
    uint32_t k0u = 0u, k1u = 42u, sx = 0u, sy = 0u;
    for (int i = 0; i <= tid; ++i) {
      uint32_t s0 = 0u, s1 = 1u; threefry2x32(k0u, k1u, s0, s1);
      uint32_t n0 = 0u, n1 = 0u; threefry2x32(k0u, k1u, n0, n1);
      sx = s0; sy = s1; k0u = n0; k1u = n1;
    }
    subs[tid] = make_uint2(sx, sy);
  }
}

// ---- shared pf(tm1) body: redundant per block, bit-exact vs validated k_pf --
// All 4 waves compute dots for 16 rows each (per-q math/shfl trees identical
// to the validated 8-wave kernel; q->wave mapping does not affect values).
// Writes (p_out, pf_out, y_out) are gated by `writer`.
__device__ __forceinline__ void pf_phase(
    int tm1, int b, int wv, int lane, bool writer,
    const float* __restrict__ h1, const float* __restrict__ obs,
    const float* __restrict__ W_obs, const float* __restrict__ b_obs_p,
    const float* __restrict__ W_out, const float* __restrict__ b_out_p,
    const float* __restrict__ p_in, float* __restrict__ p_out,
    const uint2* __restrict__ subs, float* __restrict__ d_out,
    float* logp_s, float* p1_s, float* lg_s, float* pdot_s, int* idx_s,
    float* lx_s) {
  float Wo[4], Wu[4];
#pragma unroll
  for (int m = 0; m < 4; ++m) {
    Wo[m] = W_obs[NEIN + m * 64 + lane];
    Wu[m] = W_out[m * 64 + lane];
  }
  if (wv == 0) {
    float v = obs[(b * NSEQ + tm1) * NEIN + lane] * W_obs[lane];
#pragma unroll
    for (int off = 32; off > 0; off >>= 1) v += __shfl_down(v, off, 64);
    if (lane == 0) *lx_s = v + b_obs_p[0];
  }
  {
    float hv[16][4];
#pragma unroll
    for (int u = 0; u < 16; ++u) {
      const float* hr = h1 + ((wv * 16 + u) * NBATCH + b) * NHID;
#pragma unroll
      for (int m = 0; m < 4; ++m) hv[u][m] = hr[m * 64 + lane];
    }
    // logp h-part: identical FMA order (m ascending) + identical shfl tree
#pragma unroll
    for (int u = 0; u < 16; ++u) {
      float hp = 0.f;
#pragma unroll
      for (int m = 0; m < 4; ++m) hp += hv[u][m] * Wo[m];
#pragma unroll
      for (int off = 32; off > 0; off >>= 1) hp += __shfl_down(hp, off, 64);
      if (lane == 0) logp_s[wv * 16 + u] = hp;
    }
    // W_out dot per source row (gathered later through idx: bit-identical pd)
#pragma unroll
    for (int u = 0; u < 16; ++u) {
      float pd = 0.f;
#pragma unroll
      for (int m = 0; m < 4; ++m) pd += hv[u][m] * Wu[m];
#pragma unroll
      for (int off = 32; off > 0; off >>= 1) pd += __shfl_down(pd, off, 64);
      if (lane == 0) pdot_s[wv * 16 + u] = pd;
    }
  }
  __syncthreads();

  // particle softmax (wave0, math identical)
  if (wv == 0) {
    int n = lane * NBATCH + b;  // lane = particle q
    float x = logp_s[lane] + *lx_s + p_in[n];
    float m = x;
#pragma unroll
    for (int off = 32; off > 0; off >>= 1) {
      float o = __shfl_xor(m, off, 64);
      m = o > m ? o : m;
    }
    float s = expf(x - m);
#pragma unroll
    for (int off = 32; off > 0; off >>= 1) s += __shfl_xor(s, off, 64);
    float p1 = x - m - logf(s);
    p1_s[lane] = p1;
    lg_s[lane] = logf(0.1f * expf(p1) + 0.9f / 64.f);
  }
  __syncthreads();

  // categorical via gumbel argmax; 16 q per wave, unrolled (per-q math exact)
  const uint2 sub = subs[tm1];
  {
    float v[16]; int id[16];
#pragma unroll
    for (int u = 0; u < 16; ++u) {
      int q = wv * 16 + u;
      uint32_t x0 = 0u;
      uint32_t x1 = (uint32_t)((q * NBATCH + b) * NPART + lane);
      threefry2x32(sub.x, sub.y, x0, x1);
      uint32_t bits = x0 ^ x1;
      uint32_t mant = bits >> 9;  // uniform = mant * 2^-23 (fp32-exact)
      float uu = (mant == 0u) ? 1.17549435e-38f
                              : (float)mant * 1.1920928955078125e-07f;
      float g = -logf(-logf(uu));
      v[u] = g + lg_s[lane];
      id[u] = lane;
    }
#pragma unroll
    for (int off = 32; off > 0; off >>= 1) {
#pragma unroll
      for (int u = 0; u < 16; ++u) {
        float ov = __shfl_xor(v[u], off, 64);
        int oi = __shfl_xor(id[u], off, 64);
        if (ov > v[u] || (ov == v[u] && oi < id[u])) { v[u] = ov; id[u] = oi; }
      }
    }
    if (lane == 0) {
#pragma unroll
      for (int u = 0; u < 16; ++u) idx_s[wv * 16 + u] = id[u];
    }
  }
  __syncthreads();

  // reweight + p_out + pf_out + y_out[tm1] (wave0; lane = particle q)
  if (wv == 0) {
    int src = idx_s[lane];
    float wn = 0.1f * expf(p1_s[src]) + 0.9f / 64.f;
    float lw = logf(wn);
    float m = lw;
#pragma unroll
    for (int off = 32; off > 0; off >>= 1) {
      float o = __shfl_xor(m, off, 64);
      m = o > m ? o : m;
    }
    float s = expf(lw - m);
#pragma unroll
    for (int off = 32; off > 0; off >>= 1) s += __shfl_xor(s, off, 64);
    float pn = lw - m - logf(s);
    float pd = pdot_s[src];  // bit-identical to dot(h1[src*B+b], W_out)
    if (writer) {
      p_out[lane * NBATCH + b] = pn;
      d_out[NSEQ * NBATCH + tm1 * (NPART * NBATCH) + lane * NBATCH + b] =
          lreluf(pd + b_out_p[0]);
    }
    // y(tm1) = sum_q exp(pn_q)*pd_q ; tree sum == (0 + total) of old y_acc path
    float yv = expf(pn) * pd;
#pragma unroll
    for (int off = 32; off > 0; off >>= 1) yv += __shfl_down(yv, off, 64);
    if (writer && lane == 0)
      d_out[tm1 * NBATCH + b] = lreluf(yv + b_out_p[0]);
  }
}

// ---------------- fused per-step kernel: pf(t-1) redundant + LSTM step t -----
// grid (4,128) x 256 thr, 2 blocks/CU. pf(t-1) computed by ALL blocks (each
// block derives idx locally -> no cross-block dependency, no extra launch);
// writer block (cb==0,qg==0) publishes p_cur/pf_out/y_out. Then round-7's
// validated step body: h gather via local idx, W from L2 (vmem pipe, zero
// barriers in K-loop). Per-output math bit-exact vs rounds 6/7.
__global__ __launch_bounds__(256, 2)
void k_stp(int t,
           const float* __restrict__ h_prev, const float* __restrict__ c_prev,
           float* __restrict__ h_out, float* __restrict__ c_out,
           const float* __restrict__ obs,
           const float4* __restrict__ Wih4, const float4* __restrict__ Whh4,
           const float* __restrict__ b_ih, const float* __restrict__ b_hh,
           const float* __restrict__ W_obs, const float* __restrict__ b_obs_p,
           const float* __restrict__ W_out, const float* __restrict__ b_out_p,
           const float* __restrict__ p_in, float* __restrict__ p_out,
           const uint2* __restrict__ subs, float* __restrict__ d_out) {
  __shared__ float h_s[16][NHID];      // 16 KB
  __shared__ float obs_s[NEIN];
  __shared__ int src_s[16];
  __shared__ float logp_s[NPART], p1_s[NPART], lg_s[NPART], pdot_s[NPART];
  __shared__ int idx_s[NPART];
  __shared__ float lx_s;

  const int tid = threadIdx.x;
  const int cb = blockIdx.x;   // 0..3 -> h-dims [cb*64, cb*64+64)
  const int rb = blockIdx.y;   // 0..127
  const int b = rb >> 2;
  const int qg = rb & 3;
  const int lane = tid & 63;
  const int wv = tid >> 6;           // wave id = row group (4 rows each)
  const int jglob = cb * 64 + lane;  // h-dim index [0,256)
  const bool writer = (cb == 0) && (qg == 0);

  // ---- phase pf(t-1): redundant, local idx; skipped at t==0 ----
  if (t > 0) {
    pf_phase(t - 1, b, wv, lane, writer, h_prev, obs, W_obs, b_obs_p,
             W_out, b_out_p, p_in, p_out, subs, d_out,
             logp_s, p1_s, lg_s, pdot_s, idx_s, &lx_s);
  }

  // ---- phase step t (round-7 validated body) ----
  if (tid < NEIN) obs_s[tid] = obs[(b * NSEQ + t) * NEIN + tid];
  if (tid < 16) {
    int q = qg * 16 + tid;
    src_s[tid] = ((t == 0) ? q : idx_s[q]) * NBATCH + b;  // resampled src row
  }
  __syncthreads();

  // gather h rows into LDS (coalesced; applies this step's resampling)
  for (int i = tid; i < 16 * (NHID / 4); i += 256) {
    int r = i >> 6, kq = i & 63;
    ((float4*)h_s[r])[kq] = ((const float4*)(h_prev + src_s[r] * NHID))[kq];
  }

  // x @ W_ih^T + b_ih + b_hh (same for all 16 rows: same batch b)
  float xb[4];
  {
    float4 w0 = make_float4(b_ih[jglob] + b_hh[jglob],
                            b_ih[jglob + 256] + b_hh[jglob + 256],
                            b_ih[jglob + 512] + b_hh[jglob + 512],
                            b_ih[jglob + 768] + b_hh[jglob + 768]);
    xb[0] = w0.x; xb[1] = w0.y; xb[2] = w0.z; xb[3] = w0.w;
  }
#pragma unroll 8
  for (int e = 0; e < NEIN; ++e) {
    float xv = obs_s[e];
    float4 w = Wih4[e * NHID + jglob];
    xb[0] += xv * w.x;
    xb[1] += xv * w.y;
    xb[2] += xv * w.z;
    xb[3] += xv * w.w;
  }

  float acc[4][4];
#pragma unroll
  for (int rr = 0; rr < 4; ++rr)
#pragma unroll
    for (int g = 0; g < 4; ++g) acc[rr][g] = 0.f;

  const float4* hrow4[4];
#pragma unroll
  for (int rr = 0; rr < 4; ++rr) hrow4[rr] = (const float4*)h_s[wv * 4 + rr];

  __syncthreads();  // h_s resident; K-loop below is barrier-free

  // W served straight from L2: one coalesced 16B load per (k, lane).
  const float4* __restrict__ pW = Whh4 + cb * 64 + lane;  // stride 256/k
#pragma unroll 2
  for (int k4 = 0; k4 < 64; ++k4) {   // 4 k at a time, k ascending
    float4 h4[4], w4[4];
#pragma unroll
    for (int rr = 0; rr < 4; ++rr) h4[rr] = hrow4[rr][k4];
#pragma unroll
    for (int kk = 0; kk < 4; ++kk) w4[kk] = pW[(k4 * 4 + kk) * 256];
#pragma unroll
    for (int kk = 0; kk < 4; ++kk) {
#pragma unroll
      for (int rr = 0; rr < 4; ++rr) {
        float hv = ((const float*)&h4[rr])[kk];
        acc[rr][0] += hv * w4[kk].x;
        acc[rr][1] += hv * w4[kk].y;
        acc[rr][2] += hv * w4[kk].z;
        acc[rr][3] += hv * w4[kk].w;
      }
    }
  }

#pragma unroll
  for (int rr = 0; rr < 4; ++rr) {
    int q = qg * 16 + wv * 4 + rr;
    int n = q * NBATCH + b;
    float iv = acc[rr][0] + xb[0];
    float fv = acc[rr][1] + xb[1];
    float gv = acc[rr][2] + xb[2];
    float ov = acc[rr][3] + xb[3];
    float cp = c_prev[src_s[wv * 4 + rr] * NHID + jglob];
    float si = 1.f / (1.f + expf(-iv));
    float sf = 1.f / (1.f + expf(-fv));
    float so = 1.f / (1.f + expf(-ov));
    float c1 = sf * cp + si * tanhf(gv);
    float h1 = so * tanhf(c1);
    h_out[n * NHID + jglob] = h1;
    c_out[n * NHID + jglob] = c1;
  }
}

// ---------------- final pf(NSEQ-1): one block per batch ----------------------
__global__ __launch_bounds__(256)
void k_fin(const float* __restrict__ h_last, const float* __restrict__ obs,
           const float* __restrict__ W_obs, const float* __restrict__ b_obs_p,
           const float* __restrict__ W_out, const float* __restrict__ b_out_p,
           const float* __restrict__ p_in, float* __restrict__ p_out,
           const uint2* __restrict__ subs, float* __restrict__ d_out) {
  __shared__ float logp_s[NPART], p1_s[NPART], lg_s[NPART], pdot_s[NPART];
  __shared__ int idx_s[NPART];
  __shared__ float lx_s;
  const int tid = threadIdx.x;
  const int lane = tid & 63;
  const int wv = tid >> 6;
  const int b = blockIdx.x;
  pf_phase(NSEQ - 1, b, wv, lane, true, h_last, obs, W_obs, b_obs_p,
           W_out, b_out_p, p_in, p_out, subs, d_out,
           logp_s, p1_s, lg_s, pdot_s, idx_s, &lx_s);
}

extern "C" void kernel_launch(void* const* d_in, const int* in_sizes, int n_in,
                              void* d_out, int out_size, void* d_ws, size_t ws_size,
                              hipStream_t stream) {
  const float* obs   = (const float*)d_in[0];
  const float* h0    = (const float*)d_in[1];
  const float* c0    = (const float*)d_in[2];
  const float* W_ih  = (const float*)d_in[3];
  const float* b_ih  = (const float*)d_in[4];
  const float* W_hh  = (const float*)d_in[5];
  const float* b_hh  = (const float*)d_in[6];
  const float* W_obs = (const float*)d_in[7];
  const float* b_obs = (const float*)d_in[8];
  const float* W_out = (const float*)d_in[9];
  const float* b_out = (const float*)d_in[10];
  float* out = (float*)d_out;

  char* w = (char*)d_ws;
  const size_t state = (size_t)NPART * NBATCH * NHID * sizeof(float);  // 2 MB
  float* hA = (float*)w;        w += state;
  float* hB = (float*)w;        w += state;
  float* cA = (float*)w;        w += state;
  float* cB = (float*)w;        w += state;
  float* pA = (float*)w;        w += NPART * NBATCH * sizeof(float);
  float* pB = (float*)w;        w += NPART * NBATCH * sizeof(float);
  uint2* subs = (uint2*)w;      w += NSEQ * sizeof(uint2);
  float4* Wih4 = (float4*)w;    w += NEIN * NHID * sizeof(float4);
  float4* Whh4 = (float4*)w;    w += NHID * NHID * sizeof(float4);

  k_prep<<<dim3(256), dim3(256), 0, stream>>>(h0, c0, W_ih, W_hh, hA, cA,
                                              Wih4, Whh4, pA, pB, subs);
  // p-state after pf(s) lives in buf[s&1]; prep seeds buf[1] (state after
  // pf(-1)). K(t) computes pf(t-1): reads buf[t&1], writes buf[1-(t&1)].
  for (int t = 0; t < NSEQ; ++t) {
    const float* hp = (t & 1) ? hB : hA;
    float* hn       = (t & 1) ? hA : hB;
    const float* cp = (t & 1) ? cB : cA;
    float* cn       = (t & 1) ? cA : cB;
    const float* pin = (t & 1) ? pB : pA;
    float* pout      = (t & 1) ? pA : pB;
    k_stp<<<dim3(4, 128), dim3(256), 0, stream>>>(
        t, hp, cp, hn, cn, obs, Wih4, Whh4, b_ih, b_hh,
        W_obs, b_obs, W_out, b_out, pin, pout, subs, out);
  }
  // pf(127): reads h(127) (t=127 odd -> h_out was hA) and p-state after
  // pf(126) = buf[0] = pA.
  k_fin<<<dim3(NBATCH), dim3(256), 0, stream>>>(
      hA, obs, W_obs, b_obs, W_out, b_out, pA, pB, subs, out);
}

// Round 12
// 5620.581 us; speedup vs baseline: 3.4332x; 1.0790x over previous
//
#include <hip/hip_runtime.h>
#include <stdint.h>

#define NPART 64
#define NBATCH 32
#define NSEQ 128
#define NEIN 64
#define NHID 256

// ---------------- JAX threefry2x32 (bit-exact) ----------------
__device__ __forceinline__ uint32_t rotl32(uint32_t x, uint32_t d) {
  return (x << d) | (x >> (32u - d));
}

__device__ __forceinline__ void threefry2x32(uint32_t k0, uint32_t k1,
                                             uint32_t& x0, uint32_t& x1) {
  uint32_t k2 = k0 ^ k1 ^ 0x1BD11BDAu;
  x0 += k0; x1 += k1;
#define TFR(r) { x0 += x1; x1 = rotl32(x1, r); x1 ^= x0; }
  TFR(13u) TFR(15u) TFR(26u) TFR(6u)
  x0 += k1; x1 += k2 + 1u;
  TFR(17u) TFR(29u) TFR(16u) TFR(24u)
  x0 += k2; x1 += k0 + 2u;
  TFR(13u) TFR(15u) TFR(26u) TFR(6u)
  x0 += k0; x1 += k1 + 3u;
  TFR(17u) TFR(29u) TFR(16u) TFR(24u)
  x0 += k1; x1 += k2 + 4u;
  TFR(13u) TFR(15u) TFR(26u) TFR(6u)
  x0 += k2; x1 += k0 + 5u;
#undef TFR
}

__device__ __forceinline__ float lreluf(float x) { return x >= 0.f ? x : 0.01f * x; }

// ---------------- prep: float4 gate-quad repack, state init, key chain -------
__global__ void k_prep(const float* __restrict__ h0, const float* __restrict__ c0,
                       const float* __restrict__ W_ih, const float* __restrict__ W_hh,
                       float* __restrict__ hA, float* __restrict__ cA,
                       float4* __restrict__ Wih4, float4* __restrict__ Whh4,
                       float* __restrict__ p_cur, float* __restrict__ y_acc,
                       int* __restrict__ idx_buf, uint2* __restrict__ subs) {
  int tid = blockIdx.x * blockDim.x + threadIdx.x;
  int nthr = gridDim.x * blockDim.x;
  for (int i = tid; i < NPART * NBATCH * NHID; i += nthr) {
    hA[i] = h0[i];
    cA[i] = c0[i];
  }
  // Wih4[e*256 + j] = (W_ih[j,e], W_ih[256+j,e], W_ih[512+j,e], W_ih[768+j,e])
  for (int i = tid; i < NEIN * NHID; i += nthr) {
    int e = i >> 8, j = i & 255;
    Wih4[i] = make_float4(W_ih[j * NEIN + e], W_ih[(256 + j) * NEIN + e],
                          W_ih[(512 + j) * NEIN + e], W_ih[(768 + j) * NEIN + e]);
  }
  // Whh4[k*256 + j] = (W_hh[j,k], W_hh[256+j,k], W_hh[512+j,k], W_hh[768+j,k])
  for (int i = tid; i < NHID * NHID; i += nthr) {
    int k = i >> 8, j = i & 255;
    Whh4[i] = make_float4(W_hh[j * NHID + k], W_hh[(256 + j) * NHID + k],
                          W_hh[(512 + j) * NHID + k], W_hh[(768 + j) * NHID + k]);
  }
  for (int i = tid; i < NPART * NBATCH; i += nthr) {
    p_cur[i] = -4.1588830833596715f;  // fp32(log(1/64))
    idx_buf[i] = i >> 5;              // identity resample for t=0 gather
  }
  for (int i = tid; i < NBATCH; i += nthr) y_acc[i] = 0.f;
  if (tid < NSEQ) {
    // threefry_partitionable split: key' = tf(key,(0,0)), sub = tf(key,(0,1))
    uint32_t k0u = 0u, k1u = 42u, sx = 0u, sy = 0u;
    for (int i = 0; i <= tid; ++i) {
      uint32_t s0 = 0u, s1 = 1u; threefry2x32(k0u, k1u, s0, s1);
      uint32_t n0 = 0u, n1 = 0u; threefry2x32(k0u, k1u, n0, n1);
      sx = s0; sy = s1; k0u = n0; k1u = n1;
    }
    subs[tid] = make_uint2(sx, sy);
  }
}

// ---------------- per-step: gates GEMM + LSTM pointwise (fp32 faithful) -------
// Round-7 validated structure: W NOT staged in LDS -- each wave's W read is a
// coalesced global_load_dwordx4 from the L2-resident slice (vmem pipe); grid
// (4,128) cb-fast -> each XCD sees one cb (256 KB W slice L2-resident). LDS
// carries only the h broadcasts (h_s staged once, applying the resample
// gather). K-loop has zero barriers. Change vs round 7: unroll 4 (was 2) on
// the k4 loop -> 2x outstanding W loads to cover L2 latency on the stream.
// Per-output accumulation (k ascending, one FMA per k, gates 0..3) identical
// -> trajectory bit-exact vs round 7.
__global__ __launch_bounds__(256, 2)
void k_step(int t,
            const float* __restrict__ h_prev, const float* __restrict__ c_prev,
            float* __restrict__ h_out, float* __restrict__ c_out,
            const int* __restrict__ idx_buf, const float* __restrict__ obs,
            const float4* __restrict__ Wih4, const float4* __restrict__ Whh4,
            const float* __restrict__ b_ih, const float* __restrict__ b_hh,
            float* __restrict__ y_acc, const float* __restrict__ b_out_p,
            float* __restrict__ d_out) {
  __shared__ float h_s[16][NHID];      // 16 KB
  __shared__ float obs_s[NEIN];
  __shared__ int src_s[16];
  const int tid = threadIdx.x;
  const int cb = blockIdx.x;   // 0..3 -> h-dims [cb*64, cb*64+64)
  const int rb = blockIdx.y;   // 0..127
  const int b = rb >> 2;
  const int qg = rb & 3;
  const int jloc = tid & 63;
  const int rg = tid >> 6;           // wave id = row group (4 rows each)
  const int jglob = cb * 64 + jloc;  // h-dim index [0,256)

  // finalize y_out[t-1] (y_acc filled by k_pf(t-1)); reset accumulator
  if (t > 0 && cb == 0 && rb == 0 && tid < NBATCH) {
    d_out[(t - 1) * NBATCH + tid] = lreluf(y_acc[tid] + b_out_p[0]);
    y_acc[tid] = 0.f;
  }

  if (tid < NEIN) obs_s[tid] = obs[(b * NSEQ + t) * NEIN + tid];
  if (tid < 16) {
    int q = qg * 16 + tid;
    src_s[tid] = idx_buf[q * NBATCH + b] * NBATCH + b;  // resampled source row
  }
  __syncthreads();

  // gather h rows into LDS (vectorized; applies previous step's resampling).
  // HBM/L2 latency paid ONCE here, amortized over the whole kernel.
  for (int i = tid; i < 16 * (NHID / 4); i += 256) {
    int r = i >> 6, kq = i & 63;
    ((float4*)h_s[r])[kq] = ((const float4*)(h_prev + src_s[r] * NHID))[kq];
  }

  // x @ W_ih^T + b_ih + b_hh (same for all 16 rows: same batch b)
  float xb[4];
  {
    float4 w0 = make_float4(b_ih[jglob] + b_hh[jglob],
                            b_ih[jglob + 256] + b_hh[jglob + 256],
                            b_ih[jglob + 512] + b_hh[jglob + 512],
                            b_ih[jglob + 768] + b_hh[jglob + 768]);
    xb[0] = w0.x; xb[1] = w0.y; xb[2] = w0.z; xb[3] = w0.w;
  }
#pragma unroll 8
  for (int e = 0; e < NEIN; ++e) {
    float xv = obs_s[e];
    float4 w = Wih4[e * NHID + jglob];
    xb[0] += xv * w.x;
    xb[1] += xv * w.y;
    xb[2] += xv * w.z;
    xb[3] += xv * w.w;
  }

  float acc[4][4];
#pragma unroll
  for (int rr = 0; rr < 4; ++rr)
#pragma unroll
    for (int g = 0; g < 4; ++g) acc[rr][g] = 0.f;

  const float4* hrow4[4];
#pragma unroll
  for (int rr = 0; rr < 4; ++rr) hrow4[rr] = (const float4*)h_s[rg * 4 + rr];

  __syncthreads();  // h_s resident; K-loop below is barrier-free

  // W served straight from L2: one coalesced 16B load per (k, lane).
  const float4* __restrict__ pW = Whh4 + cb * 64 + jloc;  // stride 256 quads/k
#pragma unroll 4
  for (int k4 = 0; k4 < 64; ++k4) {     // 4 k at a time, k ascending
    float4 h4[4], w4[4];
#pragma unroll
    for (int rr = 0; rr < 4; ++rr) h4[rr] = hrow4[rr][k4];
#pragma unroll
    for (int kk = 0; kk < 4; ++kk) w4[kk] = pW[(k4 * 4 + kk) * 256];
#pragma unroll
    for (int kk = 0; kk < 4; ++kk) {
#pragma unroll
      for (int rr = 0; rr < 4; ++rr) {
        float hv = ((const float*)&h4[rr])[kk];
        acc[rr][0] += hv * w4[kk].x;
        acc[rr][1] += hv * w4[kk].y;
        acc[rr][2] += hv * w4[kk].z;
        acc[rr][3] += hv * w4[kk].w;
      }
    }
  }

#pragma unroll
  for (int rr = 0; rr < 4; ++rr) {
    int q = qg * 16 + rg * 4 + rr;
    int n = q * NBATCH + b;
    float iv = acc[rr][0] + xb[0];
    float fv = acc[rr][1] + xb[1];
    float gv = acc[rr][2] + xb[2];
    float ov = acc[rr][3] + xb[3];
    float cp = c_prev[src_s[rg * 4 + rr] * NHID + jglob];
    float si = 1.f / (1.f + expf(-iv));
    float sf = 1.f / (1.f + expf(-fv));
    float so = 1.f / (1.f + expf(-ov));
    float c1 = sf * cp + si * tanhf(gv);
    float h1 = so * tanhf(c1);
    h_out[n * NHID + jglob] = h1;
    c_out[n * NHID + jglob] = c1;
  }
}

// ---------------- per-step: obs-loglik, softmax, resample, pf_out, y ---------
// one block per batch b; 512 threads = 8 waves. (unchanged, validated)
__global__ __launch_bounds__(512)
void k_pf(int t, const float* __restrict__ obs, const float* __restrict__ W_obs,
          const float* __restrict__ b_obs_p, const float* __restrict__ h1,
          float* __restrict__ p_cur, int* __restrict__ idx_buf,
          const uint2* __restrict__ subs, const float* __restrict__ W_out,
          const float* __restrict__ b_out_p, float* __restrict__ y_acc,
          float* __restrict__ d_out) {
  __shared__ float logp_s[NPART], p1_s[NPART], lg_s[NPART], pdot_s[NPART];
  __shared__ int idx_s[NPART];
  __shared__ float lx_s;
  const int tid = threadIdx.x;
  const int lane = tid & 63;
  const int wv = tid >> 6;     // 0..7
  const int b = blockIdx.x;

  // ---- Phase A: obs dot (wave0) + all 64 hp dots + all 64 pdot dots ----
  float Wo[4], Wu[4];
#pragma unroll
  for (int m = 0; m < 4; ++m) {
    Wo[m] = W_obs[NEIN + m * 64 + lane];
    Wu[m] = W_out[m * 64 + lane];
  }
  if (wv == 0) {
    float v = obs[(b * NSEQ + t) * NEIN + lane] * W_obs[lane];
#pragma unroll
    for (int off = 32; off > 0; off >>= 1) v += __shfl_down(v, off, 64);
    if (lane == 0) lx_s = v + b_obs_p[0];
  }
  {
    float hv[8][4];
#pragma unroll
    for (int u = 0; u < 8; ++u) {
      const float* hr = h1 + ((wv * 8 + u) * NBATCH + b) * NHID;
#pragma unroll
      for (int m = 0; m < 4; ++m) hv[u][m] = hr[m * 64 + lane];
    }
    // logp h-part: identical FMA order (m ascending) + identical shfl tree
#pragma unroll
    for (int u = 0; u < 8; ++u) {
      float hp = 0.f;
#pragma unroll
      for (int m = 0; m < 4; ++m) hp += hv[u][m] * Wo[m];
#pragma unroll
      for (int off = 32; off > 0; off >>= 1) hp += __shfl_down(hp, off, 64);
      if (lane == 0) logp_s[wv * 8 + u] = hp;
    }
    // W_out dot per source row (gathered later through idx: bit-identical pd)
#pragma unroll
    for (int u = 0; u < 8; ++u) {
      float pd = 0.f;
#pragma unroll
      for (int m = 0; m < 4; ++m) pd += hv[u][m] * Wu[m];
#pragma unroll
      for (int off = 32; off > 0; off >>= 1) pd += __shfl_down(pd, off, 64);
      if (lane == 0) pdot_s[wv * 8 + u] = pd;
    }
  }
  __syncthreads();

  // ---- Phase B: particle softmax (wave0, math identical) ----
  if (wv == 0) {
    int n = lane * NBATCH + b;  // lane = particle q
    float x = logp_s[lane] + lx_s + p_cur[n];
    float m = x;
#pragma unroll
    for (int off = 32; off > 0; off >>= 1) {
      float o = __shfl_xor(m, off, 64);
      m = o > m ? o : m;
    }
    float s = expf(x - m);
#pragma unroll
    for (int off = 32; off > 0; off >>= 1) s += __shfl_xor(s, off, 64);
    float p1 = x - m - logf(s);
    p1_s[lane] = p1;
    lg_s[lane] = logf(0.1f * expf(p1) + 0.9f / 64.f);
  }
  __syncthreads();

  // ---- Phase C: categorical via gumbel argmax; 8 q per wave, unrolled ----
  const uint2 sub = subs[t];
  {
    float v[8]; int id[8];
#pragma unroll
    for (int u = 0; u < 8; ++u) {
      int q = wv * 8 + u;
      uint32_t x0 = 0u;
      uint32_t x1 = (uint32_t)((q * NBATCH + b) * NPART + lane);
      threefry2x32(sub.x, sub.y, x0, x1);
      uint32_t bits = x0 ^ x1;
      uint32_t mant = bits >> 9;  // uniform = mant * 2^-23 (fp32-exact)
      float uu = (mant == 0u) ? 1.17549435e-38f
                              : (float)mant * 1.1920928955078125e-07f;
      float g = -logf(-logf(uu));
      v[u] = g + lg_s[lane];
      id[u] = lane;
    }
#pragma unroll
    for (int off = 32; off > 0; off >>= 1) {
#pragma unroll
      for (int u = 0; u < 8; ++u) {
        float ov = __shfl_xor(v[u], off, 64);
        int oi = __shfl_xor(id[u], off, 64);
        if (ov > v[u] || (ov == v[u] && oi < id[u])) { v[u] = ov; id[u] = oi; }
      }
    }
    if (lane == 0) {
#pragma unroll
      for (int u = 0; u < 8; ++u) idx_s[wv * 8 + u] = id[u];
    }
  }
  __syncthreads();

  // ---- Phase D: reweight + p_cur + pf_out + y (wave0; lane = particle q) ----
  if (wv == 0) {
    int src = idx_s[lane];
    int n = lane * NBATCH + b;
    idx_buf[n] = src;
    float wn = 0.1f * expf(p1_s[src]) + 0.9f / 64.f;
    float lw = logf(wn);
    float m = lw;
#pragma unroll
    for (int off = 32; off > 0; off >>= 1) {
      float o = __shfl_xor(m, off, 64);
      m = o > m ? o : m;
    }
    float s = expf(lw - m);
#pragma unroll
    for (int off = 32; off > 0; off >>= 1) s += __shfl_xor(s, off, 64);
    float pn = lw - m - logf(s);
    p_cur[n] = pn;
    float pd = pdot_s[src];  // bit-identical to dot(h1[src*B+b], W_out)
    d_out[NSEQ * NBATCH + t * (NPART * NBATCH) + lane * NBATCH + b] =
        lreluf(pd + b_out_p[0]);
    // y = sum_q exp(p_q) * pd_q ; block b is sole owner of y_acc[b]
    float yv = expf(pn) * pd;
#pragma unroll
    for (int off = 32; off > 0; off >>= 1) yv += __shfl_down(yv, off, 64);
    if (lane == 0) y_acc[b] += yv;
  }
}

__global__ void k_final(const float* __restrict__ y_acc,
                        const float* __restrict__ b_out_p, float* __restrict__ d_out) {
  int b = threadIdx.x;
  if (b < NBATCH) {
    d_out[(NSEQ - 1) * NBATCH + b] = lreluf(y_acc[b] + b_out_p[0]);
  }
}

extern "C" void kernel_launch(void* const* d_in, const int* in_sizes, int n_in,
                              void* d_out, int out_size, void* d_ws, size_t ws_size,
                              hipStream_t stream) {
  const float* obs   = (const float*)d_in[0];
  const float* h0    = (const float*)d_in[1];
  const float* c0    = (const float*)d_in[2];
  const float* W_ih  = (const float*)d_in[3];
  const float* b_ih  = (const float*)d_in[4];
  const float* W_hh  = (const float*)d_in[5];
  const float* b_hh  = (const float*)d_in[6];
  const float* W_obs = (const float*)d_in[7];
  const float* b_obs = (const float*)d_in[8];
  const float* W_out = (const float*)d_in[9];
  const float* b_out = (const float*)d_in[10];
  float* out = (float*)d_out;

  char* w = (char*)d_ws;
  const size_t state = (size_t)NPART * NBATCH * NHID * sizeof(float);  // 2 MB
  float* hA = (float*)w;        w += state;
  float* hB = (float*)w;        w += state;
  float* cA = (float*)w;        w += state;
  float* cB = (float*)w;        w += state;
  float* p_cur = (float*)w;     w += NPART * NBATCH * sizeof(float);
  float* y_acc = (float*)w;     w += NBATCH * sizeof(float);
  uint2* subs = (uint2*)w;      w += NSEQ * sizeof(uint2);
  float4* Wih4 = (float4*)w;    w += NEIN * NHID * sizeof(float4);
  float4* Whh4 = (float4*)w;    w += NHID * NHID * sizeof(float4);
  int* idx_buf = (int*)w;       w += NPART * NBATCH * sizeof(int);

  k_prep<<<dim3(256), dim3(256), 0, stream>>>(h0, c0, W_ih, W_hh, hA, cA, Wih4, Whh4,
                                              p_cur, y_acc, idx_buf, subs);
  for (int t = 0; t < NSEQ; ++t) {
    const float* hp = (t & 1) ? hB : hA;
    float* hn       = (t & 1) ? hA : hB;
    const float* cp = (t & 1) ? cB : cA;
    float* cn       = (t & 1) ? cA : cB;
    k_step<<<dim3(4, 128), dim3(256), 0, stream>>>(
        t, hp, cp, hn, cn, idx_buf, obs, Wih4, Whh4, b_ih, b_hh, y_acc, b_out, out);
    k_pf<<<dim3(NBATCH), dim3(512), 0, stream>>>(
        t, obs, W_obs, b_obs, hn, p_cur, idx_buf, subs, W_out, b_out, y_acc, out);
  }
  k_final<<<dim3(1), dim3(64), 0, stream>>>(y_acc, b_out, out);
}

// Round 13
// 5323.456 us; speedup vs baseline: 3.6248x; 1.0558x over previous
//
#include <hip/hip_runtime.h>
#include <stdint.h>

#define NPART 64
#define NBATCH 32
#define NSEQ 128
#define NEIN 64
#define NHID 256

// ---------------- JAX threefry2x32 (bit-exact) ----------------
__device__ __forceinline__ uint32_t rotl32(uint32_t x, uint32_t d) {
  return (x << d) | (x >> (32u - d));
}

__device__ __forceinline__ void threefry2x32(uint32_t k0, uint32_t k1,
                                             uint32_t& x0, uint32_t& x1) {
  uint32_t k2 = k0 ^ k1 ^ 0x1BD11BDAu;
  x0 += k0; x1 += k1;
#define TFR(r) { x0 += x1; x1 = rotl32(x1, r); x1 ^= x0; }
  TFR(13u) TFR(15u) TFR(26u) TFR(6u)
  x0 += k1; x1 += k2 + 1u;
  TFR(17u) TFR(29u) TFR(16u) TFR(24u)
  x0 += k2; x1 += k0 + 2u;
  TFR(13u) TFR(15u) TFR(26u) TFR(6u)
  x0 += k0; x1 += k1 + 3u;
  TFR(17u) TFR(29u) TFR(16u) TFR(24u)
  x0 += k1; x1 += k2 + 4u;
  TFR(13u) TFR(15u) TFR(26u) TFR(6u)
  x0 += k2; x1 += k0 + 5u;
#undef TFR
}

__device__ __forceinline__ float lreluf(float x) { return x >= 0.f ? x : 0.01f * x; }

// ---------------- prep: float4 gate-quad repack, state init, key chain -------
__global__ void k_prep(const float* __restrict__ h0, const float* __restrict__ c0,
                       const float* __restrict__ W_ih, const float* __restrict__ W_hh,
                       float* __restrict__ hA, float* __restrict__ cA,
                       float4* __restrict__ Wih4, float4* __restrict__ Whh4,
                       float* __restrict__ p_cur, float* __restrict__ y_acc,
                       int* __restrict__ idx_buf, uint2* __restrict__ subs) {
  int tid = blockIdx.x * blockDim.x + threadIdx.x;
  int nthr = gridDim.x * blockDim.x;
  for (int i = tid; i < NPART * NBATCH * NHID; i += nthr) {
    hA[i] = h0[i];
    cA[i] = c0[i];
  }
  // Wih4[e*256 + j] = (W_ih[j,e], W_ih[256+j,e], W_ih[512+j,e], W_ih[768+j,e])
  for (int i = tid; i < NEIN * NHID; i += nthr) {
    int e = i >> 8, j = i & 255;
    Wih4[i] = make_float4(W_ih[j * NEIN + e], W_ih[(256 + j) * NEIN + e],
                          W_ih[(512 + j) * NEIN + e], W_ih[(768 + j) * NEIN + e]);
  }
  // Whh4[k*256 + j] = (W_hh[j,k], W_hh[256+j,k], W_hh[512+j,k], W_hh[768+j,k])
  for (int i = tid; i < NHID * NHID; i += nthr) {
    int k = i >> 8, j = i & 255;
    Whh4[i] = make_float4(W_hh[j * NHID + k], W_hh[(256 + j) * NHID + k],
                          W_hh[(512 + j) * NHID + k], W_hh[(768 + j) * NHID + k]);
  }
  for (int i = tid; i < NPART * NBATCH; i += nthr) {
    p_cur[i] = -4.1588830833596715f;  // fp32(log(1/64))
    idx_buf[i] = i >> 5;              // identity resample for t=0 gather
  }
  for (int i = tid; i < NBATCH; i += nthr) y_acc[i] = 0.f;
  if (tid < NSEQ) {
    // threefry_partitionable split: key' = tf(key,(0,0)), sub = tf(key,(0,1))
    uint32_t k0u = 0u, k1u = 42u, sx = 0u, sy = 0u;
    for (int i = 0; i <= tid; ++i) {
      uint32_t s0 = 0u, s1 = 1u; threefry2x32(k0u, k1u, s0, s1);
      uint32_t n0 = 0u, n1 = 0u; threefry2x32(k0u, k1u, n0, n1);
      sx = s0; sy = s1; k0u = n0; k1u = n1;
    }
    subs[tid] = make_uint2(sx, sy);
  }
}

// ---------------- per-step: gates GEMM + LSTM pointwise (fp32 faithful) -------
// Round-12 validated structure + XCD batch-pinning: grid (128,4) rb-fast with
// b = rb&31, qg = rb>>5 -> bid%8 = rb%8 = b%8, so ALL 16 blocks of batch b
// (4 qg row-groups x 4 cb column-slices) run on XCD b%8 every step AND k_pf's
// block b is on the same XCD. Batch state (h/c, 128 KB) stays resident in ONE
// L2 across all 128 steps; resampling shuffles only within the batch -> always
// L2-local. Removes the measured ~9.6 MB/step HBM round-trip at 198 GB/s.
// Pure block-index remap: per-thread math/FMA order identical -> bit-exact.
__global__ __launch_bounds__(256, 2)
void k_step(int t,
            const float* __restrict__ h_prev, const float* __restrict__ c_prev,
            float* __restrict__ h_out, float* __restrict__ c_out,
            const int* __restrict__ idx_buf, const float* __restrict__ obs,
            const float4* __restrict__ Wih4, const float4* __restrict__ Whh4,
            const float* __restrict__ b_ih, const float* __restrict__ b_hh,
            float* __restrict__ y_acc, const float* __restrict__ b_out_p,
            float* __restrict__ d_out) {
  __shared__ float h_s[16][NHID];      // 16 KB
  __shared__ float obs_s[NEIN];
  __shared__ int src_s[16];
  const int tid = threadIdx.x;
  const int rb = blockIdx.x;   // 0..127 (fast dim -> XCD = rb%8 = b%8)
  const int cb = blockIdx.y;   // 0..3 -> h-dims [cb*64, cb*64+64)
  const int b = rb & 31;       // batch -> XCD pinned by b
  const int qg = rb >> 5;      // particle quarter
  const int jloc = tid & 63;
  const int rg = tid >> 6;           // wave id = row group (4 rows each)
  const int jglob = cb * 64 + jloc;  // h-dim index [0,256)

  // finalize y_out[t-1] (y_acc filled by k_pf(t-1)); reset accumulator
  if (t > 0 && cb == 0 && rb == 0 && tid < NBATCH) {
    d_out[(t - 1) * NBATCH + tid] = lreluf(y_acc[tid] + b_out_p[0]);
    y_acc[tid] = 0.f;
  }

  if (tid < NEIN) obs_s[tid] = obs[(b * NSEQ + t) * NEIN + tid];
  if (tid < 16) {
    int q = qg * 16 + tid;
    src_s[tid] = idx_buf[q * NBATCH + b] * NBATCH + b;  // resampled source row
  }
  __syncthreads();

  // gather h rows into LDS (vectorized; applies previous step's resampling).
  // L2-local: source rows were written by same-batch blocks on this XCD.
  for (int i = tid; i < 16 * (NHID / 4); i += 256) {
    int r = i >> 6, kq = i & 63;
    ((float4*)h_s[r])[kq] = ((const float4*)(h_prev + src_s[r] * NHID))[kq];
  }

  // x @ W_ih^T + b_ih + b_hh (same for all 16 rows: same batch b)
  float xb[4];
  {
    float4 w0 = make_float4(b_ih[jglob] + b_hh[jglob],
                            b_ih[jglob + 256] + b_hh[jglob + 256],
                            b_ih[jglob + 512] + b_hh[jglob + 512],
                            b_ih[jglob + 768] + b_hh[jglob + 768]);
    xb[0] = w0.x; xb[1] = w0.y; xb[2] = w0.z; xb[3] = w0.w;
  }
#pragma unroll 8
  for (int e = 0; e < NEIN; ++e) {
    float xv = obs_s[e];
    float4 w = Wih4[e * NHID + jglob];
    xb[0] += xv * w.x;
    xb[1] += xv * w.y;
    xb[2] += xv * w.z;
    xb[3] += xv * w.w;
  }

  float acc[4][4];
#pragma unroll
  for (int rr = 0; rr < 4; ++rr)
#pragma unroll
    for (int g = 0; g < 4; ++g) acc[rr][g] = 0.f;

  const float4* hrow4[4];
#pragma unroll
  for (int rr = 0; rr < 4; ++rr) hrow4[rr] = (const float4*)h_s[rg * 4 + rr];

  __syncthreads();  // h_s resident; K-loop below is barrier-free

  // W served straight from L2: one coalesced 16B load per (k, lane).
  const float4* __restrict__ pW = Whh4 + cb * 64 + jloc;  // stride 256 quads/k
#pragma unroll 4
  for (int k4 = 0; k4 < 64; ++k4) {     // 4 k at a time, k ascending
    float4 h4[4], w4[4];
#pragma unroll
    for (int rr = 0; rr < 4; ++rr) h4[rr] = hrow4[rr][k4];
#pragma unroll
    for (int kk = 0; kk < 4; ++kk) w4[kk] = pW[(k4 * 4 + kk) * 256];
#pragma unroll
    for (int kk = 0; kk < 4; ++kk) {
#pragma unroll
      for (int rr = 0; rr < 4; ++rr) {
        float hv = ((const float*)&h4[rr])[kk];
        acc[rr][0] += hv * w4[kk].x;
        acc[rr][1] += hv * w4[kk].y;
        acc[rr][2] += hv * w4[kk].z;
        acc[rr][3] += hv * w4[kk].w;
      }
    }
  }

#pragma unroll
  for (int rr = 0; rr < 4; ++rr) {
    int q = qg * 16 + rg * 4 + rr;
    int n = q * NBATCH + b;
    float iv = acc[rr][0] + xb[0];
    float fv = acc[rr][1] + xb[1];
    float gv = acc[rr][2] + xb[2];
    float ov = acc[rr][3] + xb[3];
    float cp = c_prev[src_s[rg * 4 + rr] * NHID + jglob];
    float si = 1.f / (1.f + expf(-iv));
    float sf = 1.f / (1.f + expf(-fv));
    float so = 1.f / (1.f + expf(-ov));
    float c1 = sf * cp + si * tanhf(gv);
    float h1 = so * tanhf(c1);
    h_out[n * NHID + jglob] = h1;
    c_out[n * NHID + jglob] = c1;
  }
}

// ---------------- per-step: obs-loglik, softmax, resample, pf_out, y ---------
// one block per batch b; 512 threads = 8 waves. (unchanged, validated)
// blockIdx.x = b -> XCD b%8, same L2 as k_step's batch-b blocks.
__global__ __launch_bounds__(512)
void k_pf(int t, const float* __restrict__ obs, const float* __restrict__ W_obs,
          const float* __restrict__ b_obs_p, const float* __restrict__ h1,
          float* __restrict__ p_cur, int* __restrict__ idx_buf,
          const uint2* __restrict__ subs, const float* __restrict__ W_out,
          const float* __restrict__ b_out_p, float* __restrict__ y_acc,
          float* __restrict__ d_out) {
  __shared__ float logp_s[NPART], p1_s[NPART], lg_s[NPART], pdot_s[NPART];
  __shared__ int idx_s[NPART];
  __shared__ float lx_s;
  const int tid = threadIdx.x;
  const int lane = tid & 63;
  const int wv = tid >> 6;     // 0..7
  const int b = blockIdx.x;

  // ---- Phase A: obs dot (wave0) + all 64 hp dots + all 64 pdot dots ----
  float Wo[4], Wu[4];
#pragma unroll
  for (int m = 0; m < 4; ++m) {
    Wo[m] = W_obs[NEIN + m * 64 + lane];
    Wu[m] = W_out[m * 64 + lane];
  }
  if (wv == 0) {
    float v = obs[(b * NSEQ + t) * NEIN + lane] * W_obs[lane];
#pragma unroll
    for (int off = 32; off > 0; off >>= 1) v += __shfl_down(v, off, 64);
    if (lane == 0) lx_s = v + b_obs_p[0];
  }
  {
    float hv[8][4];
#pragma unroll
    for (int u = 0; u < 8; ++u) {
      const float* hr = h1 + ((wv * 8 + u) * NBATCH + b) * NHID;
#pragma unroll
      for (int m = 0; m < 4; ++m) hv[u][m] = hr[m * 64 + lane];
    }
    // logp h-part: identical FMA order (m ascending) + identical shfl tree
#pragma unroll
    for (int u = 0; u < 8; ++u) {
      float hp = 0.f;
#pragma unroll
      for (int m = 0; m < 4; ++m) hp += hv[u][m] * Wo[m];
#pragma unroll
      for (int off = 32; off > 0; off >>= 1) hp += __shfl_down(hp, off, 64);
      if (lane == 0) logp_s[wv * 8 + u] = hp;
    }
    // W_out dot per source row (gathered later through idx: bit-identical pd)
#pragma unroll
    for (int u = 0; u < 8; ++u) {
      float pd = 0.f;
#pragma unroll
      for (int m = 0; m < 4; ++m) pd += hv[u][m] * Wu[m];
#pragma unroll
      for (int off = 32; off > 0; off >>= 1) pd += __shfl_down(pd, off, 64);
      if (lane == 0) pdot_s[wv * 8 + u] = pd;
    }
  }
  __syncthreads();

  // ---- Phase B: particle softmax (wave0, math identical) ----
  if (wv == 0) {
    int n = lane * NBATCH + b;  // lane = particle q
    float x = logp_s[lane] + lx_s + p_cur[n];
    float m = x;
#pragma unroll
    for (int off = 32; off > 0; off >>= 1) {
      float o = __shfl_xor(m, off, 64);
      m = o > m ? o : m;
    }
    float s = expf(x - m);
#pragma unroll
    for (int off = 32; off > 0; off >>= 1) s += __shfl_xor(s, off, 64);
    float p1 = x - m - logf(s);
    p1_s[lane] = p1;
    lg_s[lane] = logf(0.1f * expf(p1) + 0.9f / 64.f);
  }
  __syncthreads();

  // ---- Phase C: categorical via gumbel argmax; 8 q per wave, unrolled ----
  const uint2 sub = subs[t];
  {
    float v[8]; int id[8];
#pragma unroll
    for (int u = 0; u < 8; ++u) {
      int q = wv * 8 + u;
      uint32_t x0 = 0u;
      uint32_t x1 = (uint32_t)((q * NBATCH + b) * NPART + lane);
      threefry2x32(sub.x, sub.y, x0, x1);
      uint32_t bits = x0 ^ x1;
      uint32_t mant = bits >> 9;  // uniform = mant * 2^-23 (fp32-exact)
      float uu = (mant == 0u) ? 1.17549435e-38f
                              : (float)mant * 1.1920928955078125e-07f;
      float g = -logf(-logf(uu));
      v[u] = g + lg_s[lane];
      id[u] = lane;
    }
#pragma unroll
    for (int off = 32; off > 0; off >>= 1) {
#pragma unroll
      for (int u = 0; u < 8; ++u) {
        float ov = __shfl_xor(v[u], off, 64);
        int oi = __shfl_xor(id[u], off, 64);
        if (ov > v[u] || (ov == v[u] && oi < id[u])) { v[u] = ov; id[u] = oi; }
      }
    }
    if (lane == 0) {
#pragma unroll
      for (int u = 0; u < 8; ++u) idx_s[wv * 8 + u] = id[u];
    }
  }
  __syncthreads();

  // ---- Phase D: reweight + p_cur + pf_out + y (wave0; lane = particle q) ----
  if (wv == 0) {
    int src = idx_s[lane];
    int n = lane * NBATCH + b;
    idx_buf[n] = src;
    float wn = 0.1f * expf(p1_s[src]) + 0.9f / 64.f;
    float lw = logf(wn);
    float m = lw;
#pragma unroll
    for (int off = 32; off > 0; off >>= 1) {
      float o = __shfl_xor(m, off, 64);
      m = o > m ? o : m;
    }
    float s = expf(lw - m);
#pragma unroll
    for (int off = 32; off > 0; off >>= 1) s += __shfl_xor(s, off, 64);
    float pn = lw - m - logf(s);
    p_cur[n] = pn;
    float pd = pdot_s[src];  // bit-identical to dot(h1[src*B+b], W_out)
    d_out[NSEQ * NBATCH + t * (NPART * NBATCH) + lane * NBATCH + b] =
        lreluf(pd + b_out_p[0]);
    // y = sum_q exp(p_q) * pd_q ; block b is sole owner of y_acc[b]
    float yv = expf(pn) * pd;
#pragma unroll
    for (int off = 32; off > 0; off >>= 1) yv += __shfl_down(yv, off, 64);
    if (lane == 0) y_acc[b] += yv;
  }
}

__global__ void k_final(const float* __restrict__ y_acc,
                        const float* __restrict__ b_out_p, float* __restrict__ d_out) {
  int b = threadIdx.x;
  if (b < NBATCH) {
    d_out[(NSEQ - 1) * NBATCH + b] = lreluf(y_acc[b] + b_out_p[0]);
  }
}

extern "C" void kernel_launch(void* const* d_in, const int* in_sizes, int n_in,
                              void* d_out, int out_size, void* d_ws, size_t ws_size,
                              hipStream_t stream) {
  const float* obs   = (const float*)d_in[0];
  const float* h0    = (const float*)d_in[1];
  const float* c0    = (const float*)d_in[2];
  const float* W_ih  = (const float*)d_in[3];
  const float* b_ih  = (const float*)d_in[4];
  const float* W_hh  = (const float*)d_in[5];
  const float* b_hh  = (const float*)d_in[6];
  const float* W_obs = (const float*)d_in[7];
  const float* b_obs = (const float*)d_in[8];
  const float* W_out = (const float*)d_in[9];
  const float* b_out = (const float*)d_in[10];
  float* out = (float*)d_out;

  char* w = (char*)d_ws;
  const size_t state = (size_t)NPART * NBATCH * NHID * sizeof(float);  // 2 MB
  float* hA = (float*)w;        w += state;
  float* hB = (float*)w;        w += state;
  float* cA = (float*)w;        w += state;
  float* cB = (float*)w;        w += state;
  float* p_cur = (float*)w;     w += NPART * NBATCH * sizeof(float);
  float* y_acc = (float*)w;     w += NBATCH * sizeof(float);
  uint2* subs = (uint2*)w;      w += NSEQ * sizeof(uint2);
  float4* Wih4 = (float4*)w;    w += NEIN * NHID * sizeof(float4);
  float4* Whh4 = (float4*)w;    w += NHID * NHID * sizeof(float4);
  int* idx_buf = (int*)w;       w += NPART * NBATCH * sizeof(int);

  k_prep<<<dim3(256), dim3(256), 0, stream>>>(h0, c0, W_ih, W_hh, hA, cA, Wih4, Whh4,
                                              p_cur, y_acc, idx_buf, subs);
  for (int t = 0; t < NSEQ; ++t) {
    const float* hp = (t & 1) ? hB : hA;
    float* hn       = (t & 1) ? hA : hB;
    const float* cp = (t & 1) ? cB : cA;
    float* cn       = (t & 1) ? cA : cB;
    k_step<<<dim3(128, 4), dim3(256), 0, stream>>>(
        t, hp, cp, hn, cn, idx_buf, obs, Wih4, Whh4, b_ih, b_hh, y_acc, b_out, out);
    k_pf<<<dim3(NBATCH), dim3(512), 0, stream>>>(
        t, obs, W_obs, b_obs, hn, p_cur, idx_buf, subs, W_out, b_out, y_acc, out);
  }
  k_final<<<dim3(1), dim3(64), 0, stream>>>(y_acc, b_out, out);
}